// Round 1
// baseline (122.587 us; speedup 1.0000x reference)
//
#include <hip/hip_runtime.h>
#include <hip/hip_bf16.h>

#define N_ROWS 8192
#define BATCH 4096
#define DIM 256
#define INV_T 2.0f

#define MTILE 128      // rows per block
#define CCHUNK 1024    // cols per block
#define NCHUNK 8       // col chunks
#define CT 16          // cols per tile
#define LDSROW 528     // 512 data bytes + 16 pad per B-tile row
#define LDSBUF (CT * LDSROW)

typedef __attribute__((ext_vector_type(8))) short bfrag8;
typedef __attribute__((ext_vector_type(4))) float facc4;

// ---------------- Kernel A: normalize + cast to bf16 -------------------
__global__ __launch_bounds__(256) void normalize_kernel(
    const float* __restrict__ zA, const float* __restrict__ zB,
    __hip_bfloat16* __restrict__ zn) {
    int tid = threadIdx.x;
    int wave = tid >> 6, lane = tid & 63;
    int row = blockIdx.x * 4 + wave;
    const float* src = (row < BATCH) ? (zA + (size_t)row * DIM)
                                     : (zB + (size_t)(row - BATCH) * DIM);
    float4 v = ((const float4*)src)[lane];
    float ss = v.x * v.x + v.y * v.y + v.z * v.z + v.w * v.w;
    #pragma unroll
    for (int m = 32; m; m >>= 1) ss += __shfl_xor(ss, m);
    float inv = 1.0f / fmaxf(sqrtf(ss), 1e-8f);
    union { ushort4 u; __hip_bfloat16 h[4]; } o;
    o.h[0] = __float2bfloat16(v.x * inv);
    o.h[1] = __float2bfloat16(v.y * inv);
    o.h[2] = __float2bfloat16(v.z * inv);
    o.h[3] = __float2bfloat16(v.w * inv);
    ((ushort4*)zn)[(size_t)row * (DIM / 4) + lane] = o.u;
}

// ---------------- Kernel B: streaming sim + exp-sum --------------------
// grid: (64 row tiles, 8 col chunks), block 256 = 4 waves x 32 rows each.
__global__ __launch_bounds__(256, 2) void ntxent_main(
    const __hip_bfloat16* __restrict__ zn_,
    float* __restrict__ ep, float* __restrict__ pp) {
    const char* zn = (const char*)zn_;
    __shared__ char lds[2 * LDSBUF] __attribute__((aligned(16)));
    int tid = threadIdx.x, lane = tid & 63, wave = tid >> 6;
    int quad = lane >> 4, l15 = lane & 15;
    int row0 = blockIdx.x * MTILE + wave * 32;
    int chunk = blockIdx.y;
    int cc = chunk * CCHUNK;

    // A fragments: rows row0 + s*16 + l15, k = ks*32 + quad*8 + j
    bfrag8 a[2][8];
    #pragma unroll
    for (int s = 0; s < 2; s++) {
        const char* ap = zn + (size_t)(row0 + s * 16 + l15) * 512 + quad * 16;
        #pragma unroll
        for (int ks = 0; ks < 8; ks++)
            a[s][ks] = *(const bfrag8*)(ap + ks * 64);
    }

    float es[2][4] = {{0.f,0.f,0.f,0.f},{0.f,0.f,0.f,0.f}};
    float ps[2][4] = {{0.f,0.f,0.f,0.f},{0.f,0.f,0.f,0.f}};

    // staging indices: 512 chunks of 16B per tile, 2 per thread
    int col0 = tid >> 5, j0 = tid & 31;
    unsigned lofs0 = col0 * LDSROW + j0 * 16;
    unsigned lofs1 = (col0 + 8) * LDSROW + j0 * 16;
    unsigned gofs0 = col0 * 512 + j0 * 16;
    unsigned gofs1 = (col0 + 8) * 512 + j0 * 16;
    const char* gbase = zn + (size_t)cc * 512;

    { // preload tile 0
        uint4 r0 = *(const uint4*)(gbase + gofs0);
        uint4 r1 = *(const uint4*)(gbase + gofs1);
        *(uint4*)(lds + lofs0) = r0;
        *(uint4*)(lds + lofs1) = r1;
    }
    __syncthreads();

    const int NT = CCHUNK / CT;  // 64
    for (int t = 0; t < NT; t++) {
        char* cur = lds + (t & 1) * LDSBUF;
        char* nxt = lds + ((t + 1) & 1) * LDSBUF;
        uint4 s0, s1;
        if (t + 1 < NT) {
            const char* g = gbase + (size_t)(t + 1) * CT * 512;
            s0 = *(const uint4*)(g + gofs0);
            s1 = *(const uint4*)(g + gofs1);
        }
        const char* bp = cur + l15 * LDSROW + quad * 16;
        facc4 acc0 = {0.f, 0.f, 0.f, 0.f}, acc1 = {0.f, 0.f, 0.f, 0.f};
        #pragma unroll
        for (int ks = 0; ks < 8; ks++) {
            bfrag8 bf = *(const bfrag8*)(bp + ks * 64);
            acc0 = __builtin_amdgcn_mfma_f32_16x16x32_bf16(a[0][ks], bf, acc0, 0, 0, 0);
            acc1 = __builtin_amdgcn_mfma_f32_16x16x32_bf16(a[1][ks], bf, acc1, 0, 0, 0);
        }
        int gcol = cc + t * CT + l15;
        #pragma unroll
        for (int r = 0; r < 4; r++) {
            int grow = row0 + quad * 4 + r;
            float sim = acc0[r] * INV_T;
            float e = __expf(sim);
            if (gcol == grow) e = 0.0f;
            es[0][r] += e;
            if (gcol == (grow ^ BATCH)) ps[0][r] += sim;
        }
        #pragma unroll
        for (int r = 0; r < 4; r++) {
            int grow = row0 + 16 + quad * 4 + r;
            float sim = acc1[r] * INV_T;
            float e = __expf(sim);
            if (gcol == grow) e = 0.0f;
            es[1][r] += e;
            if (gcol == (grow ^ BATCH)) ps[1][r] += sim;
        }
        if (t + 1 < NT) {
            *(uint4*)(nxt + lofs0) = s0;
            *(uint4*)(nxt + lofs1) = s1;
        }
        __syncthreads();
    }

    // reduce across the 16 column-lanes of each quad
    #pragma unroll
    for (int s = 0; s < 2; s++)
        #pragma unroll
        for (int r = 0; r < 4; r++) {
            float e = es[s][r], p = ps[s][r];
            #pragma unroll
            for (int m = 1; m < 16; m <<= 1) {
                e += __shfl_xor(e, m);
                p += __shfl_xor(p, m);
            }
            if (l15 == 0) {
                int grow = row0 + s * 16 + quad * 4 + r;
                ep[(size_t)chunk * N_ROWS + grow] = e;
                pp[(size_t)chunk * N_ROWS + grow] = p;
            }
        }
}

// ---------------- Kernel C: combine + log + final reduce ---------------
__global__ __launch_bounds__(256) void finalize_kernel(
    const float* __restrict__ ep, const float* __restrict__ pp,
    float* __restrict__ out) {
    int tid = threadIdx.x;
    float acc = 0.0f;
    for (int i = tid; i < N_ROWS; i += 256) {
        float e = 0.0f, p = 0.0f;
        #pragma unroll
        for (int c = 0; c < NCHUNK; c++) {
            e += ep[(size_t)c * N_ROWS + i];
            p += pp[(size_t)c * N_ROWS + i];
        }
        acc += __logf(e) - p;
    }
    #pragma unroll
    for (int m = 32; m; m >>= 1) acc += __shfl_xor(acc, m);
    __shared__ float wsum[4];
    if ((tid & 63) == 0) wsum[tid >> 6] = acc;
    __syncthreads();
    if (tid == 0)
        out[0] = (wsum[0] + wsum[1] + wsum[2] + wsum[3]) * (1.0f / N_ROWS);
}

extern "C" void kernel_launch(void* const* d_in, const int* in_sizes, int n_in,
                              void* d_out, int out_size, void* d_ws, size_t ws_size,
                              hipStream_t stream) {
    const float* zA = (const float*)d_in[0];
    const float* zB = (const float*)d_in[1];
    float* out = (float*)d_out;
    char* ws = (char*)d_ws;
    __hip_bfloat16* zn = (__hip_bfloat16*)ws;                       // 4 MB
    float* ep = (float*)(ws + (size_t)N_ROWS * DIM * 2);            // 8*N floats
    float* pp = ep + (size_t)NCHUNK * N_ROWS;                       // 8*N floats

    normalize_kernel<<<N_ROWS / 4, 256, 0, stream>>>(zA, zB, zn);
    dim3 grid(N_ROWS / MTILE, NCHUNK);
    ntxent_main<<<grid, 256, 0, stream>>>(zn, ep, pp);
    finalize_kernel<<<1, 256, 0, stream>>>(ep, pp, out);
}

// Round 2
// 104.116 us; speedup vs baseline: 1.1774x; 1.1774x over previous
//
#include <hip/hip_runtime.h>
#include <hip/hip_bf16.h>

#define N_ROWS 8192
#define BATCH 4096
#define DIM 256

#define MTILE 256       // rows per block (4 waves x 64 rows)
#define CCHUNK 512      // cols per block
#define NCHUNK 16       // col chunks
#define CT 16           // cols per LDS tile
#define LDSROW 528      // 512 data bytes + 16 pad
#define LDSBUF (CT * LDSROW)
#define KEXP 2.8853900817779268f   // 2 * log2(e): exp(2*dot) = exp2(dot*KEXP)

typedef __attribute__((ext_vector_type(8))) short bfrag8;
typedef __attribute__((ext_vector_type(4))) float facc4;

// ---------------- Kernel A: normalize + cast to bf16 -------------------
__global__ __launch_bounds__(256) void normalize_kernel(
    const float* __restrict__ zA, const float* __restrict__ zB,
    __hip_bfloat16* __restrict__ zn) {
    int tid = threadIdx.x;
    int wave = tid >> 6, lane = tid & 63;
    int row = blockIdx.x * 4 + wave;
    const float* src = (row < BATCH) ? (zA + (size_t)row * DIM)
                                     : (zB + (size_t)(row - BATCH) * DIM);
    float4 v = ((const float4*)src)[lane];
    float ss = v.x * v.x + v.y * v.y + v.z * v.z + v.w * v.w;
    #pragma unroll
    for (int m = 32; m; m >>= 1) ss += __shfl_xor(ss, m);
    float inv = 1.0f / fmaxf(sqrtf(ss), 1e-8f);
    union { ushort4 u; __hip_bfloat16 h[4]; } o;
    o.h[0] = __float2bfloat16(v.x * inv);
    o.h[1] = __float2bfloat16(v.y * inv);
    o.h[2] = __float2bfloat16(v.z * inv);
    o.h[3] = __float2bfloat16(v.w * inv);
    ((ushort4*)zn)[(size_t)row * (DIM / 4) + lane] = o.u;
}

// ---------------- Kernel B: streaming sim + exp-sum --------------------
// grid (32 row-blocks, 16 col chunks); block 256 = 4 waves x 64 rows each.
__global__ __launch_bounds__(256, 2) void ntxent_main(
    const __hip_bfloat16* __restrict__ zn_,
    float* __restrict__ ep, float* __restrict__ pp) {
    const char* zn = (const char*)zn_;
    __shared__ char lds[2 * LDSBUF] __attribute__((aligned(16)));
    int tid = threadIdx.x, lane = tid & 63, wave = tid >> 6;
    int quad = lane >> 4, l15 = lane & 15;
    int row0 = blockIdx.x * MTILE + wave * 64;   // 64-aligned
    int chunk = blockIdx.y;
    int cc = chunk * CCHUNK;

    // A fragments: 4 tiles of 16 rows. row = row0 + s*16 + l15, k = ks*32 + quad*8 + j
    bfrag8 a[4][8];
    #pragma unroll
    for (int s = 0; s < 4; s++) {
        const char* ap = zn + (size_t)(row0 + s * 16 + l15) * 512 + quad * 16;
        #pragma unroll
        for (int ks = 0; ks < 8; ks++)
            a[s][ks] = *(const bfrag8*)(ap + ks * 64);
    }

    float es[4][4], ps[4][4];
    #pragma unroll
    for (int s = 0; s < 4; s++)
        #pragma unroll
        for (int r = 0; r < 4; r++) { es[s][r] = 0.f; ps[s][r] = 0.f; }

    // staging: 512 x 16B chunks per tile, 2 per thread
    int col0 = tid >> 5, j0 = tid & 31;
    unsigned lofs0 = col0 * LDSROW + j0 * 16;
    unsigned lofs1 = (col0 + 8) * LDSROW + j0 * 16;
    unsigned gofs0 = col0 * 512 + j0 * 16;
    unsigned gofs1 = (col0 + 8) * 512 + j0 * 16;
    const char* gbase = zn + (size_t)cc * 512;

    { // preload tile 0
        uint4 r0 = *(const uint4*)(gbase + gofs0);
        uint4 r1 = *(const uint4*)(gbase + gofs1);
        *(uint4*)(lds + lofs0) = r0;
        *(uint4*)(lds + lofs1) = r1;
    }
    __syncthreads();

    const int NT = CCHUNK / CT;  // 32
    for (int t = 0; t < NT; t++) {
        char* cur = lds + (t & 1) * LDSBUF;
        char* nxt = lds + ((t + 1) & 1) * LDSBUF;
        uint4 s0, s1;
        if (t + 1 < NT) {
            const char* g = gbase + (size_t)(t + 1) * CT * 512;
            s0 = *(const uint4*)(g + gofs0);
            s1 = *(const uint4*)(g + gofs1);
        }
        const char* bp = cur + l15 * LDSROW + quad * 16;
        bfrag8 bf[8];
        #pragma unroll
        for (int ks = 0; ks < 8; ks++)
            bf[ks] = *(const bfrag8*)(bp + ks * 64);

        facc4 acc[4];
        #pragma unroll
        for (int s = 0; s < 4; s++) acc[s] = (facc4){0.f, 0.f, 0.f, 0.f};
        #pragma unroll
        for (int ks = 0; ks < 8; ks++)
            #pragma unroll
            for (int s = 0; s < 4; s++)
                acc[s] = __builtin_amdgcn_mfma_f32_16x16x32_bf16(a[s][ks], bf[ks], acc[s], 0, 0, 0);

        int ctile = cc + t * CT;
        int gcol = ctile + l15;
        bool isdiag = (ctile >> 6) == (row0 >> 6);          // wave-uniform
        bool ispos  = (ctile >> 6) == ((row0 ^ BATCH) >> 6); // wave-uniform
        if (isdiag) {
            #pragma unroll
            for (int s = 0; s < 4; s++)
                #pragma unroll
                for (int r = 0; r < 4; r++) {
                    int grow = row0 + s * 16 + quad * 4 + r;
                    float e = __builtin_amdgcn_exp2f(acc[s][r] * KEXP);
                    if (gcol == grow) e = 0.0f;
                    es[s][r] += e;
                }
        } else if (ispos) {
            #pragma unroll
            for (int s = 0; s < 4; s++)
                #pragma unroll
                for (int r = 0; r < 4; r++) {
                    int grow = row0 + s * 16 + quad * 4 + r;
                    float d = acc[s][r];
                    es[s][r] += __builtin_amdgcn_exp2f(d * KEXP);
                    if (gcol == (grow ^ BATCH)) ps[s][r] += d;
                }
        } else {
            #pragma unroll
            for (int s = 0; s < 4; s++)
                #pragma unroll
                for (int r = 0; r < 4; r++)
                    es[s][r] += __builtin_amdgcn_exp2f(acc[s][r] * KEXP);
        }

        if (t + 1 < NT) {
            *(uint4*)(nxt + lofs0) = s0;
            *(uint4*)(nxt + lofs1) = s1;
        }
        __syncthreads();
    }

    // reduce across the 16 column-lanes; write per-chunk expsum, pos once.
    bool poswave = (((row0 ^ BATCH) >> 9) == chunk);  // this chunk holds pos cols
    #pragma unroll
    for (int s = 0; s < 4; s++)
        #pragma unroll
        for (int r = 0; r < 4; r++) {
            float e = es[s][r], p = ps[s][r];
            #pragma unroll
            for (int m = 1; m < 16; m <<= 1) {
                e += __shfl_xor(e, m);
                p += __shfl_xor(p, m);
            }
            if (l15 == 0) {
                int grow = row0 + s * 16 + quad * 4 + r;
                ep[(size_t)chunk * N_ROWS + grow] = e;
                if (poswave) pp[grow] = p;   // raw dot; scaled in finalize
            }
        }
}

// ---------------- Kernel C: combine + log + final reduce ---------------
__global__ __launch_bounds__(256) void finalize_kernel(
    const float* __restrict__ ep, const float* __restrict__ pp,
    float* __restrict__ out) {
    int tid = threadIdx.x;
    int i = blockIdx.x * 256 + tid;
    float e = 0.0f;
    #pragma unroll
    for (int c = 0; c < NCHUNK; c++) e += ep[(size_t)c * N_ROWS + i];
    float v = __logf(e) - 2.0f * pp[i];
    #pragma unroll
    for (int m = 32; m; m >>= 1) v += __shfl_xor(v, m);
    __shared__ float wsum[4];
    if ((tid & 63) == 0) wsum[tid >> 6] = v;
    __syncthreads();
    if (tid == 0)
        atomicAdd(out, (wsum[0] + wsum[1] + wsum[2] + wsum[3]) * (1.0f / N_ROWS));
}

extern "C" void kernel_launch(void* const* d_in, const int* in_sizes, int n_in,
                              void* d_out, int out_size, void* d_ws, size_t ws_size,
                              hipStream_t stream) {
    const float* zA = (const float*)d_in[0];
    const float* zB = (const float*)d_in[1];
    float* out = (float*)d_out;
    char* ws = (char*)d_ws;
    __hip_bfloat16* zn = (__hip_bfloat16*)ws;                       // 4 MB
    float* ep = (float*)(ws + (size_t)N_ROWS * DIM * 2);            // 16*8192 floats
    float* pp = ep + (size_t)NCHUNK * N_ROWS;                       // 8192 floats

    hipMemsetAsync(out, 0, sizeof(float), stream);
    normalize_kernel<<<N_ROWS / 4, 256, 0, stream>>>(zA, zB, zn);
    dim3 grid(N_ROWS / MTILE, NCHUNK);
    ntxent_main<<<grid, 256, 0, stream>>>(zn, ep, pp);
    finalize_kernel<<<N_ROWS / 256, 256, 0, stream>>>(ep, pp, out);
}